// Round 7
// baseline (441.884 us; speedup 1.0000x reference)
//
#include <hip/hip_runtime.h>

#define LL 16384
#define HH 128
#define WW 128
#define CC 64
#define NH 8
#define EPSF 1e-7f
#define KVCHUNKS 32

// ---------------- Kernel A: qkv 1x1 conv + bias (+relu on q,k) ----------------
// grid (64 pixel-blocks, B, 3 sections), block 256
__global__ void qkv_kernel(const float* __restrict__ x, const float* __restrict__ w,
                           const float* __restrict__ bias,
                           float* __restrict__ q, float* __restrict__ k, float* __restrict__ v) {
    const int pix = blockIdx.x * 256 + threadIdx.x;
    const int b   = blockIdx.y;
    const int sec = blockIdx.z;

    float xr[64];
    const float* xb = x + (size_t)b * CC * LL + pix;
#pragma unroll
    for (int c = 0; c < 64; ++c) xr[c] = xb[(size_t)c * LL];

    float* dst = (sec == 0) ? q : (sec == 1) ? k : v;
    const bool do_relu = (sec < 2);

    for (int ol = 0; ol < 64; ++ol) {
        const int o = sec * 64 + ol;
        const float* wr = w + o * 64;           // wave-uniform -> scalar loads
        float a0 = 0.f, a1 = 0.f, a2 = 0.f, a3 = 0.f;
#pragma unroll
        for (int c = 0; c < 64; c += 4) {
            a0 += xr[c]     * wr[c];
            a1 += xr[c + 1] * wr[c + 1];
            a2 += xr[c + 2] * wr[c + 2];
            a3 += xr[c + 3] * wr[c + 3];
        }
        float acc = (a0 + a1) + (a2 + a3) + bias[o];
        if (do_relu) acc = fmaxf(acc, 0.f);
        dst[(size_t)(b * 64 + ol) * LL + pix] = acc;
    }
}

// ---------------- Kernel B: KV/KS partials, K staged in LDS ----------------
// grid (32 chunks of 4 rows, NH, B) = 1024 blocks, block 256.
// 32-lane group per k-channel c; lanes 0-15 accumulate cp 0-3, lanes 16-31 cp 4-7.
__global__ void kv_kernel(const float* __restrict__ k, const float* __restrict__ v,
                          float* __restrict__ KVp) {
    const int chunk = blockIdx.x;
    const int h = blockIdx.y;
    const int b = blockIdx.z;
    const int tid = threadIdx.x;
    const int c  = tid >> 5;          // 0..7
    const int s  = tid & 31;
    const int half = s >> 4;          // 0/1 -> cp half
    const int sl   = s & 15;
    const int cpb  = half * 4;

    // K tile with halo: 8 ch x 6 rows x 130 cols
    __shared__ float klds[8][6][130];

    {   // stage: 6240 elements, coalesced along cols, zero-padded outside image
        const float* kb = k + ((size_t)(b * 64) + 8 * h) * LL;
        for (int t = tid; t < 8 * 6 * 130; t += 256) {
            const int ch = t / 780;
            const int r1 = t - ch * 780;
            const int lr = r1 / 130;
            const int cx = r1 - lr * 130;
            const int gy = chunk * 4 + lr - 1;
            const int gx = cx - 1;
            const bool ok = (gy >= 0 && gy < HH && gx >= 0 && gx < WW);
            klds[ch][lr][cx] = ok ? kb[(size_t)ch * LL + gy * WW + gx] : 0.f;
        }
    }
    __syncthreads();

    const float* vb = v + ((size_t)(b * 64) + 8 * h + cpb) * LL;

    float kv4[9][4] = {{0.f}};
    float ks[9] = {0.f};

    for (int r = 0; r < 4; ++r) {
        const int y = chunk * 4 + r;
        for (int g = 0; g < 8; ++g) {
            const int col = g * 16 + sl;
            float vv[4];
#pragma unroll
            for (int cp = 0; cp < 4; ++cp) vv[cp] = vb[(size_t)cp * LL + y * WW + col];
            float k9[9];
#pragma unroll
            for (int dy = 0; dy < 3; ++dy)
#pragma unroll
                for (int dx = 0; dx < 3; ++dx)
                    k9[dy * 3 + dx] = klds[c][r + dy][col + dx];
#pragma unroll
            for (int p = 0; p < 9; ++p) {
                ks[p] += k9[p];
#pragma unroll
                for (int cp = 0; cp < 4; ++cp)
                    kv4[p][cp] = fmaf(k9[p], vv[cp], kv4[p][cp]);
            }
        }
    }

#pragma unroll
    for (int p = 0; p < 9; ++p) {
#pragma unroll
        for (int m = 8; m >= 1; m >>= 1) ks[p] += __shfl_xor(ks[p], m);
#pragma unroll
        for (int cp = 0; cp < 4; ++cp) {
#pragma unroll
            for (int m = 8; m >= 1; m >>= 1) kv4[p][cp] += __shfl_xor(kv4[p][cp], m);
        }
    }

    if (sl == 0) {
        float* dst = KVp + (((size_t)(b * NH + h) * KVCHUNKS) + chunk) * 648;
#pragma unroll
        for (int p = 0; p < 9; ++p) {
#pragma unroll
            for (int cp = 0; cp < 4; ++cp)
                dst[(c * 9 + p) * 8 + cpb + cp] = kv4[p][cp];
            if (half == 0) dst[576 + c * 9 + p] = ks[p];
        }
    }
}

// ---------------- Kernel B2: reduce 32 chunk-partials -> KV, KS ----------------
__global__ void kv_finalize(const float* __restrict__ KVp,
                            float* __restrict__ KV, float* __restrict__ KS) {
    const int bh = blockIdx.x;
    const float* src = KVp + (size_t)bh * KVCHUNKS * 648;
    for (int idx = threadIdx.x; idx < 648; idx += 256) {
        float s0 = 0.f, s1 = 0.f, s2 = 0.f, s3 = 0.f;
#pragma unroll
        for (int ch = 0; ch < KVCHUNKS; ch += 4) {
            s0 += src[(ch + 0) * 648 + idx];
            s1 += src[(ch + 1) * 648 + idx];
            s2 += src[(ch + 2) * 648 + idx];
            s3 += src[(ch + 3) * 648 + idx];
        }
        const float sum = (s0 + s1) + (s2 + s3);
        if (idx < 576) KV[(size_t)bh * 576 + idx] = sum;
        else           KS[(size_t)bh * 72 + (idx - 576)] = sum;
    }
}

// ---------------- Kernel C: out = (Q_unfold @ KV) / (Q_unfold @ Ksum + EPS) ----------------
// grid (128 rows, NH, B), block 128 (thread = column)
__global__ void attn_kernel(const float* __restrict__ q, const float* __restrict__ KV,
                            const float* __restrict__ KS, float* __restrict__ ao) {
    const int y = blockIdx.x;
    const int h = blockIdx.y;
    const int b = blockIdx.z;
    const int col = threadIdx.x;

    float out[8] = {0.f};
    float den = 0.f;
    const int kvbase = (b * NH + h) * 8;

    for (int c = 0; c < 8; ++c) {
        const float* qc = q + ((size_t)(b * 64) + 8 * h + c) * LL;
        float q9[9];
#pragma unroll
        for (int dy = -1; dy <= 1; ++dy)
#pragma unroll
            for (int dx = -1; dx <= 1; ++dx) {
                const int yy = y + dy, xx = col + dx;
                const bool ok = (yy >= 0 && yy < HH && xx >= 0 && xx < WW);
                q9[(dy + 1) * 3 + (dx + 1)] = ok ? qc[yy * WW + xx] : 0.f;
            }
        const float* kvr = KV + ((size_t)(kvbase + c) * 9) * 8;  // wave-uniform -> scalar loads
        const float* ksr = KS + (size_t)(kvbase + c) * 9;
#pragma unroll
        for (int p = 0; p < 9; ++p) {
            const float qv = q9[p];
            den += qv * ksr[p];
#pragma unroll
            for (int cp = 0; cp < 8; ++cp) out[cp] += qv * kvr[p * 8 + cp];
        }
    }
    const float inv = 1.f / (den + EPSF);
    const int pix = y * WW + col;
#pragma unroll
    for (int cp = 0; cp < 8; ++cp)
        ao[((size_t)(b * 64) + h * 8 + cp) * LL + pix] = out[cp] * inv;
}

// ---------------- Kernel D: 3x3 conv 64->64 + bias, 4 rows/thread ----------------
// grid (64, B): blockIdx.x = rowtile*2 + colhalf; 32 row-tiles of 4 rows.
// Block 256 = 4 waves; wave wv -> couts [16wv,16wv+16); lane = col (64 cols).
// Thread computes 16 couts x 4 rows. Pixels AND weights staged in LDS.
#define CI_CHUNK 8
__global__ void conv_kernel(const float* __restrict__ ao, const float* __restrict__ w,
                            const float* __restrict__ bias, float* __restrict__ out) {
    const int bx = blockIdx.x;
    const int y0 = (bx >> 1) * 4;
    const int colbase = (bx & 1) * 64;
    const int b = blockIdx.y;
    const int colx = threadIdx.x & 63;
    const int wv   = threadIdx.x >> 6;   // 0..3, wave-uniform

    __shared__ float plds[CI_CHUNK][6][72];    // pixels: 4 rows + halo -> 6 rows, 13824 B
    __shared__ float wlds[CI_CHUNK][64][12];   // weights padded to 12 (16B-aligned float4), 24576 B

    float acc[16][4];
#pragma unroll
    for (int j = 0; j < 16; ++j)
#pragma unroll
        for (int r = 0; r < 4; ++r) acc[j][r] = 0.f;

    const float* aob = ao + (size_t)b * 64 * LL;

    for (int cc = 0; cc < 64; cc += CI_CHUNK) {
        __syncthreads();   // previous chunk's reads complete before overwrite
        // stage pixels: 8 ci x 6 rows = 48 (ci,ry) pairs, one per wave per iter
#pragma unroll
        for (int it = 0; it < 12; ++it) {
            const int pair = it * 4 + wv;         // 0..47
            const int ci   = pair / 6;
            const int ry   = pair - ci * 6;
            const int gy   = y0 + ry - 1;
            const bool yok = (gy >= 0 && gy < HH);
            const float* src = aob + (size_t)(cc + ci) * LL + gy * WW;
            plds[ci][ry][1 + colx] = yok ? src[colbase + colx] : 0.f;
            if (colx == 0) {
                const int gx = colbase - 1;
                plds[ci][ry][0] = (yok && gx >= 0) ? src[gx] : 0.f;
            }
            if (colx == 63) {
                const int gx = colbase + 64;
                plds[ci][ry][65] = (yok && gx < WW) ? src[gx] : 0.f;
            }
        }
        // stage weights: 8 ci x 64 co x 9 = 4608 dwords, 18 per thread
        for (int t = threadIdx.x; t < CI_CHUNK * 64 * 9; t += 256) {
            const int ci = t / 576;           // 64*9
            const int r  = t - ci * 576;
            const int co = r / 9;
            const int p  = r - co * 9;
            wlds[ci][co][p] = w[((co * 64) + (cc + ci)) * 9 + p];
        }
        __syncthreads();

        for (int ci = 0; ci < CI_CHUNK; ++ci) {
            // 6-row x 3-col window for this thread's column
            float a[6][3];
#pragma unroll
            for (int lr = 0; lr < 6; ++lr)
#pragma unroll
                for (int dx = 0; dx < 3; ++dx)
                    a[lr][dx] = plds[ci][lr][colx + dx];   // stride-1: conflict-free
#pragma unroll
            for (int j = 0; j < 16; ++j) {
                const int co = wv * 16 + j;   // wave-uniform -> LDS broadcast
                const float4 w0 = *(const float4*)&wlds[ci][co][0];
                const float4 w1 = *(const float4*)&wlds[ci][co][4];
                const float  w8 = wlds[ci][co][8];
#pragma unroll
                for (int r = 0; r < 4; ++r) {
                    float t0 = fmaf(a[r + 0][0], w0.x, acc[j][r]);
                    t0 = fmaf(a[r + 0][1], w0.y, t0);
                    t0 = fmaf(a[r + 0][2], w0.z, t0);
                    t0 = fmaf(a[r + 1][0], w0.w, t0);
                    t0 = fmaf(a[r + 1][1], w1.x, t0);
                    t0 = fmaf(a[r + 1][2], w1.y, t0);
                    t0 = fmaf(a[r + 2][0], w1.z, t0);
                    t0 = fmaf(a[r + 2][1], w1.w, t0);
                    acc[j][r] = fmaf(a[r + 2][2], w8, t0);
                }
            }
        }
    }

#pragma unroll
    for (int j = 0; j < 16; ++j) {
        const int o = wv * 16 + j;
        const float bs = bias[o];
        float* dst = out + ((size_t)b * 64 + o) * LL + y0 * WW + colbase + colx;
#pragma unroll
        for (int r = 0; r < 4; ++r)
            dst[r * WW] = acc[j][r] + bs;
    }
}

extern "C" void kernel_launch(void* const* d_in, const int* in_sizes, int n_in,
                              void* d_out, int out_size, void* d_ws, size_t ws_size,
                              hipStream_t stream) {
    const float* x      = (const float*)d_in[0];
    const float* qkv_w  = (const float*)d_in[1];
    const float* qkv_b  = (const float*)d_in[2];
    const float* proj_w = (const float*)d_in[3];
    const float* proj_b = (const float*)d_in[4];
    float* out = (float*)d_out;
    float* ws  = (float*)d_ws;

    const size_t n1 = (size_t)4 * 64 * LL;      // one B*C*L fp32 plane set
    float* qb  = ws;
    float* kb  = ws + n1;
    float* vb  = ws + 2 * n1;
    float* aob = ws + 3 * n1;
    float* KV  = ws + 4 * n1;                   // 4*8*8*9*8 = 18432 floats
    float* KS  = KV + 4 * 8 * 8 * 9 * 8;        // 4*8*8*9  = 2304 floats
    float* KVp = KS + 4 * 8 * 8 * 9;            // 32*32*648 floats

    qkv_kernel<<<dim3(64, 4, 3), 256, 0, stream>>>(x, qkv_w, qkv_b, qb, kb, vb);
    kv_kernel<<<dim3(KVCHUNKS, NH, 4), 256, 0, stream>>>(kb, vb, KVp);
    kv_finalize<<<32, 256, 0, stream>>>(KVp, KV, KS);
    attn_kernel<<<dim3(128, NH, 4), 128, 0, stream>>>(qb, KV, KS, aob);
    conv_kernel<<<dim3(64, 4), 256, 0, stream>>>(aob, proj_w, proj_b, out);
}

// Round 8
// 222.159 us; speedup vs baseline: 1.9890x; 1.9890x over previous
//
#include <hip/hip_runtime.h>
#include <hip/hip_fp16.h>

#define LL 16384
#define HH 128
#define WW 128
#define CC 64
#define NH 8
#define EPSF 1e-7f
#define KVCHUNKS 32

typedef __attribute__((ext_vector_type(8))) _Float16 f16x8;
typedef __attribute__((ext_vector_type(4))) float f32x4;

// ---------------- Kernel A: qkv 1x1 conv + bias (+relu on q,k) ----------------
__global__ void qkv_kernel(const float* __restrict__ x, const float* __restrict__ w,
                           const float* __restrict__ bias,
                           float* __restrict__ q, float* __restrict__ k, float* __restrict__ v) {
    const int pix = blockIdx.x * 256 + threadIdx.x;
    const int b   = blockIdx.y;
    const int sec = blockIdx.z;

    float xr[64];
    const float* xb = x + (size_t)b * CC * LL + pix;
#pragma unroll
    for (int c = 0; c < 64; ++c) xr[c] = xb[(size_t)c * LL];

    float* dst = (sec == 0) ? q : (sec == 1) ? k : v;
    const bool do_relu = (sec < 2);

    for (int ol = 0; ol < 64; ++ol) {
        const int o = sec * 64 + ol;
        const float* wr = w + o * 64;           // wave-uniform -> scalar loads
        float a0 = 0.f, a1 = 0.f, a2 = 0.f, a3 = 0.f;
#pragma unroll
        for (int c = 0; c < 64; c += 4) {
            a0 += xr[c]     * wr[c];
            a1 += xr[c + 1] * wr[c + 1];
            a2 += xr[c + 2] * wr[c + 2];
            a3 += xr[c + 3] * wr[c + 3];
        }
        float acc = (a0 + a1) + (a2 + a3) + bias[o];
        if (do_relu) acc = fmaxf(acc, 0.f);
        dst[(size_t)(b * 64 + ol) * LL + pix] = acc;
    }
}

// ---------------- Kernel B: KV/KS partials, K staged in LDS ----------------
__global__ void kv_kernel(const float* __restrict__ k, const float* __restrict__ v,
                          float* __restrict__ KVp) {
    const int chunk = blockIdx.x;
    const int h = blockIdx.y;
    const int b = blockIdx.z;
    const int tid = threadIdx.x;
    const int c  = tid >> 5;
    const int s  = tid & 31;
    const int half = s >> 4;
    const int sl   = s & 15;
    const int cpb  = half * 4;

    __shared__ float klds[8][6][130];

    {
        const float* kb = k + ((size_t)(b * 64) + 8 * h) * LL;
        for (int t = tid; t < 8 * 6 * 130; t += 256) {
            const int ch = t / 780;
            const int r1 = t - ch * 780;
            const int lr = r1 / 130;
            const int cx = r1 - lr * 130;
            const int gy = chunk * 4 + lr - 1;
            const int gx = cx - 1;
            const bool ok = (gy >= 0 && gy < HH && gx >= 0 && gx < WW);
            klds[ch][lr][cx] = ok ? kb[(size_t)ch * LL + gy * WW + gx] : 0.f;
        }
    }
    __syncthreads();

    const float* vb = v + ((size_t)(b * 64) + 8 * h + cpb) * LL;

    float kv4[9][4] = {{0.f}};
    float ks[9] = {0.f};

    for (int r = 0; r < 4; ++r) {
        const int y = chunk * 4 + r;
        for (int g = 0; g < 8; ++g) {
            const int col = g * 16 + sl;
            float vv[4];
#pragma unroll
            for (int cp = 0; cp < 4; ++cp) vv[cp] = vb[(size_t)cp * LL + y * WW + col];
            float k9[9];
#pragma unroll
            for (int dy = 0; dy < 3; ++dy)
#pragma unroll
                for (int dx = 0; dx < 3; ++dx)
                    k9[dy * 3 + dx] = klds[c][r + dy][col + dx];
#pragma unroll
            for (int p = 0; p < 9; ++p) {
                ks[p] += k9[p];
#pragma unroll
                for (int cp = 0; cp < 4; ++cp)
                    kv4[p][cp] = fmaf(k9[p], vv[cp], kv4[p][cp]);
            }
        }
    }

#pragma unroll
    for (int p = 0; p < 9; ++p) {
#pragma unroll
        for (int m = 8; m >= 1; m >>= 1) ks[p] += __shfl_xor(ks[p], m);
#pragma unroll
        for (int cp = 0; cp < 4; ++cp) {
#pragma unroll
            for (int m = 8; m >= 1; m >>= 1) kv4[p][cp] += __shfl_xor(kv4[p][cp], m);
        }
    }

    if (sl == 0) {
        float* dst = KVp + (((size_t)(b * NH + h) * KVCHUNKS) + chunk) * 648;
#pragma unroll
        for (int p = 0; p < 9; ++p) {
#pragma unroll
            for (int cp = 0; cp < 4; ++cp)
                dst[(c * 9 + p) * 8 + cpb + cp] = kv4[p][cp];
            if (half == 0) dst[576 + c * 9 + p] = ks[p];
        }
    }
}

// ---------------- Kernel B2: reduce 32 chunk-partials -> KV, KS ----------------
__global__ void kv_finalize(const float* __restrict__ KVp,
                            float* __restrict__ KV, float* __restrict__ KS) {
    const int bh = blockIdx.x;
    const float* src = KVp + (size_t)bh * KVCHUNKS * 648;
    for (int idx = threadIdx.x; idx < 648; idx += 256) {
        float s0 = 0.f, s1 = 0.f, s2 = 0.f, s3 = 0.f;
#pragma unroll
        for (int ch = 0; ch < KVCHUNKS; ch += 4) {
            s0 += src[(ch + 0) * 648 + idx];
            s1 += src[(ch + 1) * 648 + idx];
            s2 += src[(ch + 2) * 648 + idx];
            s3 += src[(ch + 3) * 648 + idx];
        }
        const float sum = (s0 + s1) + (s2 + s3);
        if (idx < 576) KV[(size_t)bh * 576 + idx] = sum;
        else           KS[(size_t)bh * 72 + (idx - 576)] = sum;
    }
}

// ---------------- Kernel C: out = (Q_unfold @ KV) / (Q_unfold @ Ksum + EPS) ----------------
__global__ void attn_kernel(const float* __restrict__ q, const float* __restrict__ KV,
                            const float* __restrict__ KS, float* __restrict__ ao) {
    const int y = blockIdx.x;
    const int h = blockIdx.y;
    const int b = blockIdx.z;
    const int col = threadIdx.x;

    float out[8] = {0.f};
    float den = 0.f;
    const int kvbase = (b * NH + h) * 8;

    for (int c = 0; c < 8; ++c) {
        const float* qc = q + ((size_t)(b * 64) + 8 * h + c) * LL;
        float q9[9];
#pragma unroll
        for (int dy = -1; dy <= 1; ++dy)
#pragma unroll
            for (int dx = -1; dx <= 1; ++dx) {
                const int yy = y + dy, xx = col + dx;
                const bool ok = (yy >= 0 && yy < HH && xx >= 0 && xx < WW);
                q9[(dy + 1) * 3 + (dx + 1)] = ok ? qc[yy * WW + xx] : 0.f;
            }
        const float* kvr = KV + ((size_t)(kvbase + c) * 9) * 8;
        const float* ksr = KS + (size_t)(kvbase + c) * 9;
#pragma unroll
        for (int p = 0; p < 9; ++p) {
            const float qv = q9[p];
            den += qv * ksr[p];
#pragma unroll
            for (int cp = 0; cp < 8; ++cp) out[cp] += qv * kvr[p * 8 + cp];
        }
    }
    const float inv = 1.f / (den + EPSF);
    const int pix = y * WW + col;
#pragma unroll
    for (int cp = 0; cp < 8; ++cp)
        ao[((size_t)(b * 64) + h * 8 + cp) * LL + pix] = out[cp] * inv;
}

// ---------------- Kernel D: 3x3 conv 64->64 + bias via MFMA f16 hi/lo split ----------
// GEMM: C[64 co][128 pix] = W[64][K=1024] @ P[K][128] per (row y, batch b).
// K = 64 ci x 16 (9 taps zero-padded to 16). 32 ksteps of K=32 (2 ci each).
// Block 256 = 4 waves; wave wv owns pix [32*wv, 32*wv+32) -> 4 co-tiles x 2 pix-tiles.
// f16 split: W ~ Wh+Wl, P ~ Ph+Pl; acc += Wh*Ph + Wh*Pl + Wl*Ph  (lo*lo dropped).
__global__ __launch_bounds__(256, 2) void conv_kernel(const float* __restrict__ ao,
                                                      const float* __restrict__ w,
                                                      const float* __restrict__ bias,
                                                      float* __restrict__ out) {
    const int y = blockIdx.x;       // image row
    const int b = blockIdx.y;
    const int tid = threadIdx.x;
    const int lane = tid & 63;
    const int wv = tid >> 6;        // 0..3

    __shared__ _Float16 plds[2][2][128][40];   // [buf][hi/lo][pix][k(32)+pad] 40960 B
    __shared__ _Float16 wlds[2][2][64][40];    // [buf][hi/lo][co][k(32)+pad]  20480 B

    f32x4 acc[4][2];
#pragma unroll
    for (int ct = 0; ct < 4; ++ct)
#pragma unroll
        for (int pt = 0; pt < 2; ++pt) acc[ct][pt] = (f32x4)0.f;

    const float* aob = ao + (size_t)b * 64 * LL;

    // ---- staging: build P (patches) and W (weights) f16 hi/lo for kstep ks ----
    auto stage = [&](int nb, int ks) {
        const int ci0 = ks * 2;
        {   // P: one thread per (pix, cisel): 16 k-values (9 real taps + 7 zero)
            const int pix = tid & 127;
            const int cisel = tid >> 7;
            const float* src = aob + (size_t)(ci0 + cisel) * LL;
            float v16[16];
#pragma unroll
            for (int dy = 0; dy < 3; ++dy) {
                const int yy = y + dy - 1;
#pragma unroll
                for (int dx = 0; dx < 3; ++dx) {
                    const int xx = pix + dx - 1;
                    const bool ok = (yy >= 0 && yy < HH && xx >= 0 && xx < WW);
                    v16[dy * 3 + dx] = ok ? src[yy * WW + xx] : 0.f;
                }
            }
#pragma unroll
            for (int j = 9; j < 16; ++j) v16[j] = 0.f;
            _Float16 hi[16], lo[16];
#pragma unroll
            for (int j = 0; j < 16; ++j) {
                const _Float16 h = (_Float16)v16[j];
                hi[j] = h;
                lo[j] = (_Float16)(v16[j] - (float)h);
            }
            *(f16x8*)&plds[nb][0][pix][cisel * 16]     = *(f16x8*)&hi[0];
            *(f16x8*)&plds[nb][0][pix][cisel * 16 + 8] = *(f16x8*)&hi[8];
            *(f16x8*)&plds[nb][1][pix][cisel * 16]     = *(f16x8*)&lo[0];
            *(f16x8*)&plds[nb][1][pix][cisel * 16 + 8] = *(f16x8*)&lo[8];
        }
        {   // W: one thread per (co, cisel, half): 8 k-values
            const int co = tid & 63;
            const int cisel = (tid >> 6) & 1;
            const int hlf = tid >> 7;
            const float* wr = w + ((size_t)co * 64 + ci0 + cisel) * 9;
            _Float16 h8[8], l8[8];
#pragma unroll
            for (int j = 0; j < 8; ++j) {
                const int p = hlf * 8 + j;
                const float vv = (p < 9) ? wr[p] : 0.f;
                const _Float16 h = (_Float16)vv;
                h8[j] = h;
                l8[j] = (_Float16)(vv - (float)h);
            }
            *(f16x8*)&wlds[nb][0][co][cisel * 16 + hlf * 8] = *(f16x8*)&h8[0];
            *(f16x8*)&wlds[nb][1][co][cisel * 16 + hlf * 8] = *(f16x8*)&l8[0];
        }
    };

    stage(0, 0);
    __syncthreads();

    const int g8 = (lane >> 4) * 8;   // k-offset of this lane's fragment
    const int rl = lane & 15;         // row (A) / col (B) within 16

    for (int ks = 0; ks < 32; ++ks) {
        const int cb = ks & 1;
        if (ks < 31) stage(cb ^ 1, ks + 1);

        f16x8 ah[4], al[4], bh[2], bl[2];
#pragma unroll
        for (int ct = 0; ct < 4; ++ct) {
            ah[ct] = *(const f16x8*)&wlds[cb][0][ct * 16 + rl][g8];
            al[ct] = *(const f16x8*)&wlds[cb][1][ct * 16 + rl][g8];
        }
#pragma unroll
        for (int pt = 0; pt < 2; ++pt) {
            bh[pt] = *(const f16x8*)&plds[cb][0][wv * 32 + pt * 16 + rl][g8];
            bl[pt] = *(const f16x8*)&plds[cb][1][wv * 32 + pt * 16 + rl][g8];
        }
#pragma unroll
        for (int ct = 0; ct < 4; ++ct)
#pragma unroll
            for (int pt = 0; pt < 2; ++pt) {
                acc[ct][pt] = __builtin_amdgcn_mfma_f32_16x16x32_f16(ah[ct], bh[pt], acc[ct][pt], 0, 0, 0);
                acc[ct][pt] = __builtin_amdgcn_mfma_f32_16x16x32_f16(ah[ct], bl[pt], acc[ct][pt], 0, 0, 0);
                acc[ct][pt] = __builtin_amdgcn_mfma_f32_16x16x32_f16(al[ct], bh[pt], acc[ct][pt], 0, 0, 0);
            }
        __syncthreads();
    }

    // epilogue: D[r][c]: c = lane&15 (pix), r = (lane>>4)*4 + j (co)
#pragma unroll
    for (int ct = 0; ct < 4; ++ct) {
        const int co_b = ct * 16 + (lane >> 4) * 4;
#pragma unroll
        for (int pt = 0; pt < 2; ++pt) {
            const int px = wv * 32 + pt * 16 + rl;
#pragma unroll
            for (int j = 0; j < 4; ++j) {
                const int co = co_b + j;
                out[((size_t)b * 64 + co) * LL + y * WW + px] = acc[ct][pt][j] + bias[co];
            }
        }
    }
}

extern "C" void kernel_launch(void* const* d_in, const int* in_sizes, int n_in,
                              void* d_out, int out_size, void* d_ws, size_t ws_size,
                              hipStream_t stream) {
    const float* x      = (const float*)d_in[0];
    const float* qkv_w  = (const float*)d_in[1];
    const float* qkv_b  = (const float*)d_in[2];
    const float* proj_w = (const float*)d_in[3];
    const float* proj_b = (const float*)d_in[4];
    float* out = (float*)d_out;
    float* ws  = (float*)d_ws;

    const size_t n1 = (size_t)4 * 64 * LL;      // one B*C*L fp32 plane set
    float* qb  = ws;
    float* kb  = ws + n1;
    float* vb  = ws + 2 * n1;
    float* aob = ws + 3 * n1;
    float* KV  = ws + 4 * n1;                   // 4*8*8*9*8 = 18432 floats
    float* KS  = KV + 4 * 8 * 8 * 9 * 8;        // 4*8*8*9  = 2304 floats
    float* KVp = KS + 4 * 8 * 8 * 9;            // 32*32*648 floats

    qkv_kernel<<<dim3(64, 4, 3), 256, 0, stream>>>(x, qkv_w, qkv_b, qb, kb, vb);
    kv_kernel<<<dim3(KVCHUNKS, NH, 4), 256, 0, stream>>>(kb, vb, KVp);
    kv_finalize<<<32, 256, 0, stream>>>(KVp, KV, KS);
    attn_kernel<<<dim3(128, NH, 4), 128, 0, stream>>>(qb, KV, KS, aob);
    conv_kernel<<<dim3(128, 4), 256, 0, stream>>>(aob, proj_w, proj_b, out);
}

// Round 9
// 133.795 us; speedup vs baseline: 3.3027x; 1.6604x over previous
//
#include <hip/hip_runtime.h>
#include <hip/hip_fp16.h>

#define LL 16384
#define HH 128
#define WW 128
#define CC 64
#define NH 8
#define EPSF 1e-7f
#define KVCHUNKS 32

typedef __attribute__((ext_vector_type(8))) _Float16 f16x8;
typedef __attribute__((ext_vector_type(4))) float f32x4;

// ---------------- Kernel A: qkv 1x1 conv + bias (+relu on q,k) via MFMA hi/lo ----------
// GEMM per (pixblock, b, sec): C[64 co][128 pix] = W[64][64] @ X[64][128 pix].
// K = 64 ci -> 2 ksteps of 32. f16 split: acc += Wh*Xh + Wh*Xl + Wl*Xh.
// Block 256 = 4 waves; wave wv owns pix [32wv, 32wv+32): 4 co-tiles x 2 pix-tiles.
__global__ void qkv_kernel(const float* __restrict__ x, const float* __restrict__ w,
                           const float* __restrict__ bias,
                           float* __restrict__ q, float* __restrict__ k, float* __restrict__ v) {
    const int pix0 = blockIdx.x * 128;
    const int b    = blockIdx.y;
    const int sec  = blockIdx.z;
    const int tid  = threadIdx.x;
    const int lane = tid & 63;
    const int wv   = tid >> 6;

    __shared__ _Float16 xh[128][72], xl[128][72];   // [pix][ci], 36864 B
    __shared__ _Float16 wh[64][72],  wl[64][72];    // [co][ci],  18432 B

    // stage X: coalesced along pixels
    {
        const float* xb = x + (size_t)b * CC * LL + pix0;
        for (int idx = tid; idx < 64 * 128; idx += 256) {
            const int ci = idx >> 7;
            const int px = idx & 127;
            const float vv = xb[(size_t)ci * LL + px];
            const _Float16 h = (_Float16)vv;
            xh[px][ci] = h;
            xl[px][ci] = (_Float16)(vv - (float)h);
        }
    }
    // stage W for this section: coalesced along ci
    {
        const float* wsec = w + (size_t)sec * 64 * 64;
        for (int idx = tid; idx < 64 * 64; idx += 256) {
            const int co = idx >> 6;
            const int ci = idx & 63;
            const float vv = wsec[co * 64 + ci];
            const _Float16 h = (_Float16)vv;
            wh[co][ci] = h;
            wl[co][ci] = (_Float16)(vv - (float)h);
        }
    }
    __syncthreads();

    f32x4 acc[4][2];
#pragma unroll
    for (int ct = 0; ct < 4; ++ct)
#pragma unroll
        for (int pt = 0; pt < 2; ++pt) acc[ct][pt] = (f32x4)0.f;

    const int g8 = (lane >> 4) * 8;
    const int rl = lane & 15;

#pragma unroll
    for (int ks = 0; ks < 2; ++ks) {
        const int kb = ks * 32 + g8;
        f16x8 ah[4], al[4], bh[2], bl[2];
#pragma unroll
        for (int ct = 0; ct < 4; ++ct) {
            ah[ct] = *(const f16x8*)&wh[ct * 16 + rl][kb];
            al[ct] = *(const f16x8*)&wl[ct * 16 + rl][kb];
        }
#pragma unroll
        for (int pt = 0; pt < 2; ++pt) {
            bh[pt] = *(const f16x8*)&xh[wv * 32 + pt * 16 + rl][kb];
            bl[pt] = *(const f16x8*)&xl[wv * 32 + pt * 16 + rl][kb];
        }
#pragma unroll
        for (int ct = 0; ct < 4; ++ct)
#pragma unroll
            for (int pt = 0; pt < 2; ++pt) {
                acc[ct][pt] = __builtin_amdgcn_mfma_f32_16x16x32_f16(ah[ct], bh[pt], acc[ct][pt], 0, 0, 0);
                acc[ct][pt] = __builtin_amdgcn_mfma_f32_16x16x32_f16(ah[ct], bl[pt], acc[ct][pt], 0, 0, 0);
                acc[ct][pt] = __builtin_amdgcn_mfma_f32_16x16x32_f16(al[ct], bh[pt], acc[ct][pt], 0, 0, 0);
            }
    }

    float* dst = (sec == 0) ? q : (sec == 1) ? k : v;
    const bool do_relu = (sec < 2);
#pragma unroll
    for (int ct = 0; ct < 4; ++ct) {
        const int co_b = ct * 16 + (lane >> 4) * 4;
#pragma unroll
        for (int pt = 0; pt < 2; ++pt) {
            const int px = pix0 + wv * 32 + pt * 16 + rl;
#pragma unroll
            for (int j = 0; j < 4; ++j) {
                const int co = co_b + j;
                float val = acc[ct][pt][j] + bias[sec * 64 + co];
                if (do_relu) val = fmaxf(val, 0.f);
                dst[((size_t)b * 64 + co) * LL + px] = val;
            }
        }
    }
}

// ---------------- Kernel B: KV/KS partials, K staged in LDS ----------------
__global__ void kv_kernel(const float* __restrict__ k, const float* __restrict__ v,
                          float* __restrict__ KVp) {
    const int chunk = blockIdx.x;
    const int h = blockIdx.y;
    const int b = blockIdx.z;
    const int tid = threadIdx.x;
    const int c  = tid >> 5;
    const int s  = tid & 31;
    const int half = s >> 4;
    const int sl   = s & 15;
    const int cpb  = half * 4;

    __shared__ float klds[8][6][130];

    {
        const float* kb = k + ((size_t)(b * 64) + 8 * h) * LL;
        for (int t = tid; t < 8 * 6 * 130; t += 256) {
            const int ch = t / 780;
            const int r1 = t - ch * 780;
            const int lr = r1 / 130;
            const int cx = r1 - lr * 130;
            const int gy = chunk * 4 + lr - 1;
            const int gx = cx - 1;
            const bool ok = (gy >= 0 && gy < HH && gx >= 0 && gx < WW);
            klds[ch][lr][cx] = ok ? kb[(size_t)ch * LL + gy * WW + gx] : 0.f;
        }
    }
    __syncthreads();

    const float* vb = v + ((size_t)(b * 64) + 8 * h + cpb) * LL;

    float kv4[9][4] = {{0.f}};
    float ks[9] = {0.f};

    for (int r = 0; r < 4; ++r) {
        const int y = chunk * 4 + r;
        for (int g = 0; g < 8; ++g) {
            const int col = g * 16 + sl;
            float vv[4];
#pragma unroll
            for (int cp = 0; cp < 4; ++cp) vv[cp] = vb[(size_t)cp * LL + y * WW + col];
            float k9[9];
#pragma unroll
            for (int dy = 0; dy < 3; ++dy)
#pragma unroll
                for (int dx = 0; dx < 3; ++dx)
                    k9[dy * 3 + dx] = klds[c][r + dy][col + dx];
#pragma unroll
            for (int p = 0; p < 9; ++p) {
                ks[p] += k9[p];
#pragma unroll
                for (int cp = 0; cp < 4; ++cp)
                    kv4[p][cp] = fmaf(k9[p], vv[cp], kv4[p][cp]);
            }
        }
    }

#pragma unroll
    for (int p = 0; p < 9; ++p) {
#pragma unroll
        for (int m = 8; m >= 1; m >>= 1) ks[p] += __shfl_xor(ks[p], m);
#pragma unroll
        for (int cp = 0; cp < 4; ++cp) {
#pragma unroll
            for (int m = 8; m >= 1; m >>= 1) kv4[p][cp] += __shfl_xor(kv4[p][cp], m);
        }
    }

    if (sl == 0) {
        float* dst = KVp + (((size_t)(b * NH + h) * KVCHUNKS) + chunk) * 648;
#pragma unroll
        for (int p = 0; p < 9; ++p) {
#pragma unroll
            for (int cp = 0; cp < 4; ++cp)
                dst[(c * 9 + p) * 8 + cpb + cp] = kv4[p][cp];
            if (half == 0) dst[576 + c * 9 + p] = ks[p];
        }
    }
}

// ---------------- Kernel B2: reduce 32 chunk-partials -> KV, KS ----------------
__global__ void kv_finalize(const float* __restrict__ KVp,
                            float* __restrict__ KV, float* __restrict__ KS) {
    const int bh = blockIdx.x;
    const float* src = KVp + (size_t)bh * KVCHUNKS * 648;
    for (int idx = threadIdx.x; idx < 648; idx += 256) {
        float s0 = 0.f, s1 = 0.f, s2 = 0.f, s3 = 0.f;
#pragma unroll
        for (int ch = 0; ch < KVCHUNKS; ch += 4) {
            s0 += src[(ch + 0) * 648 + idx];
            s1 += src[(ch + 1) * 648 + idx];
            s2 += src[(ch + 2) * 648 + idx];
            s3 += src[(ch + 3) * 648 + idx];
        }
        const float sum = (s0 + s1) + (s2 + s3);
        if (idx < 576) KV[(size_t)bh * 576 + idx] = sum;
        else           KS[(size_t)bh * 72 + (idx - 576)] = sum;
    }
}

// ---------------- Kernel C: out = (Q_unfold @ KV) / (Q_unfold @ Ksum + EPS) ----------------
__global__ void attn_kernel(const float* __restrict__ q, const float* __restrict__ KV,
                            const float* __restrict__ KS, float* __restrict__ ao) {
    const int y = blockIdx.x;
    const int h = blockIdx.y;
    const int b = blockIdx.z;
    const int col = threadIdx.x;

    float out[8] = {0.f};
    float den = 0.f;
    const int kvbase = (b * NH + h) * 8;

    for (int c = 0; c < 8; ++c) {
        const float* qc = q + ((size_t)(b * 64) + 8 * h + c) * LL;
        float q9[9];
#pragma unroll
        for (int dy = -1; dy <= 1; ++dy)
#pragma unroll
            for (int dx = -1; dx <= 1; ++dx) {
                const int yy = y + dy, xx = col + dx;
                const bool ok = (yy >= 0 && yy < HH && xx >= 0 && xx < WW);
                q9[(dy + 1) * 3 + (dx + 1)] = ok ? qc[yy * WW + xx] : 0.f;
            }
        const float* kvr = KV + ((size_t)(kvbase + c) * 9) * 8;
        const float* ksr = KS + (size_t)(kvbase + c) * 9;
#pragma unroll
        for (int p = 0; p < 9; ++p) {
            const float qv = q9[p];
            den += qv * ksr[p];
#pragma unroll
            for (int cp = 0; cp < 8; ++cp) out[cp] += qv * kvr[p * 8 + cp];
        }
    }
    const float inv = 1.f / (den + EPSF);
    const int pix = y * WW + col;
#pragma unroll
    for (int cp = 0; cp < 8; ++cp)
        ao[((size_t)(b * 64) + h * 8 + cp) * LL + pix] = out[cp] * inv;
}

// ---------------- Kernel D: 3x3 conv 64->64 + bias via MFMA f16 hi/lo split ----------
__global__ __launch_bounds__(256, 2) void conv_kernel(const float* __restrict__ ao,
                                                      const float* __restrict__ w,
                                                      const float* __restrict__ bias,
                                                      float* __restrict__ out) {
    const int y = blockIdx.x;       // image row
    const int b = blockIdx.y;
    const int tid = threadIdx.x;
    const int lane = tid & 63;
    const int wv = tid >> 6;        // 0..3

    __shared__ _Float16 plds[2][2][128][40];   // [buf][hi/lo][pix][k(32)+pad]
    __shared__ _Float16 wlds[2][2][64][40];    // [buf][hi/lo][co][k(32)+pad]

    f32x4 acc[4][2];
#pragma unroll
    for (int ct = 0; ct < 4; ++ct)
#pragma unroll
        for (int pt = 0; pt < 2; ++pt) acc[ct][pt] = (f32x4)0.f;

    const float* aob = ao + (size_t)b * 64 * LL;

    auto stage = [&](int nb, int ks) {
        const int ci0 = ks * 2;
        {   // P: one thread per (pix, cisel): 16 k-values (9 real taps + 7 zero)
            const int pix = tid & 127;
            const int cisel = tid >> 7;
            const float* src = aob + (size_t)(ci0 + cisel) * LL;
            float v16[16];
#pragma unroll
            for (int dy = 0; dy < 3; ++dy) {
                const int yy = y + dy - 1;
#pragma unroll
                for (int dx = 0; dx < 3; ++dx) {
                    const int xx = pix + dx - 1;
                    const bool ok = (yy >= 0 && yy < HH && xx >= 0 && xx < WW);
                    v16[dy * 3 + dx] = ok ? src[yy * WW + xx] : 0.f;
                }
            }
#pragma unroll
            for (int j = 9; j < 16; ++j) v16[j] = 0.f;
            _Float16 hi[16], lo[16];
#pragma unroll
            for (int j = 0; j < 16; ++j) {
                const _Float16 h = (_Float16)v16[j];
                hi[j] = h;
                lo[j] = (_Float16)(v16[j] - (float)h);
            }
            *(f16x8*)&plds[nb][0][pix][cisel * 16]     = *(f16x8*)&hi[0];
            *(f16x8*)&plds[nb][0][pix][cisel * 16 + 8] = *(f16x8*)&hi[8];
            *(f16x8*)&plds[nb][1][pix][cisel * 16]     = *(f16x8*)&lo[0];
            *(f16x8*)&plds[nb][1][pix][cisel * 16 + 8] = *(f16x8*)&lo[8];
        }
        {   // W: one thread per (co, cisel, half): 8 k-values
            const int co = tid & 63;
            const int cisel = (tid >> 6) & 1;
            const int hlf = tid >> 7;
            const float* wr = w + ((size_t)co * 64 + ci0 + cisel) * 9;
            _Float16 h8[8], l8[8];
#pragma unroll
            for (int j = 0; j < 8; ++j) {
                const int p = hlf * 8 + j;
                const float vv = (p < 9) ? wr[p] : 0.f;
                const _Float16 h = (_Float16)vv;
                h8[j] = h;
                l8[j] = (_Float16)(vv - (float)h);
            }
            *(f16x8*)&wlds[nb][0][co][cisel * 16 + hlf * 8] = *(f16x8*)&h8[0];
            *(f16x8*)&wlds[nb][1][co][cisel * 16 + hlf * 8] = *(f16x8*)&l8[0];
        }
    };

    stage(0, 0);
    __syncthreads();

    const int g8 = (lane >> 4) * 8;
    const int rl = lane & 15;

    for (int ks = 0; ks < 32; ++ks) {
        const int cb = ks & 1;
        if (ks < 31) stage(cb ^ 1, ks + 1);

        f16x8 ah[4], al[4], bh[2], bl[2];
#pragma unroll
        for (int ct = 0; ct < 4; ++ct) {
            ah[ct] = *(const f16x8*)&wlds[cb][0][ct * 16 + rl][g8];
            al[ct] = *(const f16x8*)&wlds[cb][1][ct * 16 + rl][g8];
        }
#pragma unroll
        for (int pt = 0; pt < 2; ++pt) {
            bh[pt] = *(const f16x8*)&plds[cb][0][wv * 32 + pt * 16 + rl][g8];
            bl[pt] = *(const f16x8*)&plds[cb][1][wv * 32 + pt * 16 + rl][g8];
        }
#pragma unroll
        for (int ct = 0; ct < 4; ++ct)
#pragma unroll
            for (int pt = 0; pt < 2; ++pt) {
                acc[ct][pt] = __builtin_amdgcn_mfma_f32_16x16x32_f16(ah[ct], bh[pt], acc[ct][pt], 0, 0, 0);
                acc[ct][pt] = __builtin_amdgcn_mfma_f32_16x16x32_f16(ah[ct], bl[pt], acc[ct][pt], 0, 0, 0);
                acc[ct][pt] = __builtin_amdgcn_mfma_f32_16x16x32_f16(al[ct], bh[pt], acc[ct][pt], 0, 0, 0);
            }
        __syncthreads();
    }

#pragma unroll
    for (int ct = 0; ct < 4; ++ct) {
        const int co_b = ct * 16 + (lane >> 4) * 4;
#pragma unroll
        for (int pt = 0; pt < 2; ++pt) {
            const int px = wv * 32 + pt * 16 + rl;
#pragma unroll
            for (int j = 0; j < 4; ++j) {
                const int co = co_b + j;
                out[((size_t)b * 64 + co) * LL + y * WW + px] = acc[ct][pt][j] + bias[co];
            }
        }
    }
}

extern "C" void kernel_launch(void* const* d_in, const int* in_sizes, int n_in,
                              void* d_out, int out_size, void* d_ws, size_t ws_size,
                              hipStream_t stream) {
    const float* x      = (const float*)d_in[0];
    const float* qkv_w  = (const float*)d_in[1];
    const float* qkv_b  = (const float*)d_in[2];
    const float* proj_w = (const float*)d_in[3];
    const float* proj_b = (const float*)d_in[4];
    float* out = (float*)d_out;
    float* ws  = (float*)d_ws;

    const size_t n1 = (size_t)4 * 64 * LL;      // one B*C*L fp32 plane set
    float* qb  = ws;
    float* kb  = ws + n1;
    float* vb  = ws + 2 * n1;
    float* aob = ws + 3 * n1;
    float* KV  = ws + 4 * n1;                   // 4*8*8*9*8 = 18432 floats
    float* KS  = KV + 4 * 8 * 8 * 9 * 8;        // 4*8*8*9  = 2304 floats
    float* KVp = KS + 4 * 8 * 8 * 9;            // 32*32*648 floats

    qkv_kernel<<<dim3(128, 4, 3), 256, 0, stream>>>(x, qkv_w, qkv_b, qb, kb, vb);
    kv_kernel<<<dim3(KVCHUNKS, NH, 4), 256, 0, stream>>>(kb, vb, KVp);
    kv_finalize<<<32, 256, 0, stream>>>(KVp, KV, KS);
    attn_kernel<<<dim3(128, NH, 4), 128, 0, stream>>>(qb, KV, KS, aob);
    conv_kernel<<<dim3(128, 4), 256, 0, stream>>>(aob, proj_w, proj_b, out);
}

// Round 10
// 117.713 us; speedup vs baseline: 3.7539x; 1.1366x over previous
//
#include <hip/hip_runtime.h>
#include <hip/hip_fp16.h>

#define LL 16384
#define HH 128
#define WW 128
#define CC 64
#define NH 8
#define EPSF 1e-7f
#define KVCHUNKS 32

typedef __attribute__((ext_vector_type(8))) _Float16 f16x8;
typedef __attribute__((ext_vector_type(4))) float f32x4;
typedef __attribute__((ext_vector_type(8))) unsigned short u16x8;

// ---------------- Kernel A: qkv 1x1 conv + bias (+relu on q,k) via MFMA hi/lo ----------
__global__ void qkv_kernel(const float* __restrict__ x, const float* __restrict__ w,
                           const float* __restrict__ bias,
                           float* __restrict__ q, float* __restrict__ k, float* __restrict__ v) {
    const int pix0 = blockIdx.x * 128;
    const int b    = blockIdx.y;
    const int sec  = blockIdx.z;
    const int tid  = threadIdx.x;
    const int lane = tid & 63;
    const int wv   = tid >> 6;

    __shared__ _Float16 xh[128][72], xl[128][72];
    __shared__ _Float16 wh[64][72],  wl[64][72];

    {
        const float* xb = x + (size_t)b * CC * LL + pix0;
        for (int idx = tid; idx < 64 * 128; idx += 256) {
            const int ci = idx >> 7;
            const int px = idx & 127;
            const float vv = xb[(size_t)ci * LL + px];
            const _Float16 h = (_Float16)vv;
            xh[px][ci] = h;
            xl[px][ci] = (_Float16)(vv - (float)h);
        }
    }
    {
        const float* wsec = w + (size_t)sec * 64 * 64;
        for (int idx = tid; idx < 64 * 64; idx += 256) {
            const int co = idx >> 6;
            const int ci = idx & 63;
            const float vv = wsec[co * 64 + ci];
            const _Float16 h = (_Float16)vv;
            wh[co][ci] = h;
            wl[co][ci] = (_Float16)(vv - (float)h);
        }
    }
    __syncthreads();

    f32x4 acc[4][2];
#pragma unroll
    for (int ct = 0; ct < 4; ++ct)
#pragma unroll
        for (int pt = 0; pt < 2; ++pt) acc[ct][pt] = (f32x4)0.f;

    const int g8 = (lane >> 4) * 8;
    const int rl = lane & 15;

#pragma unroll
    for (int ks = 0; ks < 2; ++ks) {
        const int kb = ks * 32 + g8;
        f16x8 ah[4], al[4], bh[2], bl[2];
#pragma unroll
        for (int ct = 0; ct < 4; ++ct) {
            ah[ct] = *(const f16x8*)&wh[ct * 16 + rl][kb];
            al[ct] = *(const f16x8*)&wl[ct * 16 + rl][kb];
        }
#pragma unroll
        for (int pt = 0; pt < 2; ++pt) {
            bh[pt] = *(const f16x8*)&xh[wv * 32 + pt * 16 + rl][kb];
            bl[pt] = *(const f16x8*)&xl[wv * 32 + pt * 16 + rl][kb];
        }
#pragma unroll
        for (int ct = 0; ct < 4; ++ct)
#pragma unroll
            for (int pt = 0; pt < 2; ++pt) {
                acc[ct][pt] = __builtin_amdgcn_mfma_f32_16x16x32_f16(ah[ct], bh[pt], acc[ct][pt], 0, 0, 0);
                acc[ct][pt] = __builtin_amdgcn_mfma_f32_16x16x32_f16(ah[ct], bl[pt], acc[ct][pt], 0, 0, 0);
                acc[ct][pt] = __builtin_amdgcn_mfma_f32_16x16x32_f16(al[ct], bh[pt], acc[ct][pt], 0, 0, 0);
            }
    }

    float* dst = (sec == 0) ? q : (sec == 1) ? k : v;
    const bool do_relu = (sec < 2);
#pragma unroll
    for (int ct = 0; ct < 4; ++ct) {
        const int co_b = ct * 16 + (lane >> 4) * 4;
#pragma unroll
        for (int pt = 0; pt < 2; ++pt) {
            const int px = pix0 + wv * 32 + pt * 16 + rl;
#pragma unroll
            for (int j = 0; j < 4; ++j) {
                const int co = co_b + j;
                float val = acc[ct][pt][j] + bias[sec * 64 + co];
                if (do_relu) val = fmaxf(val, 0.f);
                dst[((size_t)b * 64 + co) * LL + px] = val;
            }
        }
    }
}

// ---------------- Kernel B: KV/KS partials, K staged in LDS ----------------
__global__ void kv_kernel(const float* __restrict__ k, const float* __restrict__ v,
                          float* __restrict__ KVp) {
    const int chunk = blockIdx.x;
    const int h = blockIdx.y;
    const int b = blockIdx.z;
    const int tid = threadIdx.x;
    const int c  = tid >> 5;
    const int s  = tid & 31;
    const int half = s >> 4;
    const int sl   = s & 15;
    const int cpb  = half * 4;

    __shared__ float klds[8][6][130];

    {
        const float* kb = k + ((size_t)(b * 64) + 8 * h) * LL;
        for (int t = tid; t < 8 * 6 * 130; t += 256) {
            const int ch = t / 780;
            const int r1 = t - ch * 780;
            const int lr = r1 / 130;
            const int cx = r1 - lr * 130;
            const int gy = chunk * 4 + lr - 1;
            const int gx = cx - 1;
            const bool ok = (gy >= 0 && gy < HH && gx >= 0 && gx < WW);
            klds[ch][lr][cx] = ok ? kb[(size_t)ch * LL + gy * WW + gx] : 0.f;
        }
    }
    __syncthreads();

    const float* vb = v + ((size_t)(b * 64) + 8 * h + cpb) * LL;

    float kv4[9][4] = {{0.f}};
    float ks[9] = {0.f};

    for (int r = 0; r < 4; ++r) {
        const int y = chunk * 4 + r;
        for (int g = 0; g < 8; ++g) {
            const int col = g * 16 + sl;
            float vv[4];
#pragma unroll
            for (int cp = 0; cp < 4; ++cp) vv[cp] = vb[(size_t)cp * LL + y * WW + col];
            float k9[9];
#pragma unroll
            for (int dy = 0; dy < 3; ++dy)
#pragma unroll
                for (int dx = 0; dx < 3; ++dx)
                    k9[dy * 3 + dx] = klds[c][r + dy][col + dx];
#pragma unroll
            for (int p = 0; p < 9; ++p) {
                ks[p] += k9[p];
#pragma unroll
                for (int cp = 0; cp < 4; ++cp)
                    kv4[p][cp] = fmaf(k9[p], vv[cp], kv4[p][cp]);
            }
        }
    }

#pragma unroll
    for (int p = 0; p < 9; ++p) {
#pragma unroll
        for (int m = 8; m >= 1; m >>= 1) ks[p] += __shfl_xor(ks[p], m);
#pragma unroll
        for (int cp = 0; cp < 4; ++cp) {
#pragma unroll
            for (int m = 8; m >= 1; m >>= 1) kv4[p][cp] += __shfl_xor(kv4[p][cp], m);
        }
    }

    if (sl == 0) {
        float* dst = KVp + (((size_t)(b * NH + h) * KVCHUNKS) + chunk) * 648;
#pragma unroll
        for (int p = 0; p < 9; ++p) {
#pragma unroll
            for (int cp = 0; cp < 4; ++cp)
                dst[(c * 9 + p) * 8 + cpb + cp] = kv4[p][cp];
            if (half == 0) dst[576 + c * 9 + p] = ks[p];
        }
    }
}

// ---------------- Kernel B2: reduce 32 chunk-partials -> KV, KS ----------------
__global__ void kv_finalize(const float* __restrict__ KVp,
                            float* __restrict__ KV, float* __restrict__ KS) {
    const int bh = blockIdx.x;
    const float* src = KVp + (size_t)bh * KVCHUNKS * 648;
    for (int idx = threadIdx.x; idx < 648; idx += 256) {
        float s0 = 0.f, s1 = 0.f, s2 = 0.f, s3 = 0.f;
#pragma unroll
        for (int ch = 0; ch < KVCHUNKS; ch += 4) {
            s0 += src[(ch + 0) * 648 + idx];
            s1 += src[(ch + 1) * 648 + idx];
            s2 += src[(ch + 2) * 648 + idx];
            s3 += src[(ch + 3) * 648 + idx];
        }
        const float sum = (s0 + s1) + (s2 + s3);
        if (idx < 576) KV[(size_t)bh * 576 + idx] = sum;
        else           KS[(size_t)bh * 72 + (idx - 576)] = sum;
    }
}

// ---------------- Kernel C: attn, writes packed f16 hi/lo ----------------
__global__ void attn_kernel(const float* __restrict__ q, const float* __restrict__ KV,
                            const float* __restrict__ KS, unsigned int* __restrict__ aohl) {
    const int y = blockIdx.x;
    const int h = blockIdx.y;
    const int b = blockIdx.z;
    const int col = threadIdx.x;

    float out[8] = {0.f};
    float den = 0.f;
    const int kvbase = (b * NH + h) * 8;

    for (int c = 0; c < 8; ++c) {
        const float* qc = q + ((size_t)(b * 64) + 8 * h + c) * LL;
        float q9[9];
#pragma unroll
        for (int dy = -1; dy <= 1; ++dy)
#pragma unroll
            for (int dx = -1; dx <= 1; ++dx) {
                const int yy = y + dy, xx = col + dx;
                const bool ok = (yy >= 0 && yy < HH && xx >= 0 && xx < WW);
                q9[(dy + 1) * 3 + (dx + 1)] = ok ? qc[yy * WW + xx] : 0.f;
            }
        const float* kvr = KV + ((size_t)(kvbase + c) * 9) * 8;
        const float* ksr = KS + (size_t)(kvbase + c) * 9;
#pragma unroll
        for (int p = 0; p < 9; ++p) {
            const float qv = q9[p];
            den += qv * ksr[p];
#pragma unroll
            for (int cp = 0; cp < 8; ++cp) out[cp] += qv * kvr[p * 8 + cp];
        }
    }
    const float inv = 1.f / (den + EPSF);
    const int pix = y * WW + col;
#pragma unroll
    for (int cp = 0; cp < 8; ++cp) {
        const float val = out[cp] * inv;
        const _Float16 hf = (_Float16)val;
        const _Float16 lf = (_Float16)(val - (float)hf);
        unsigned short hb, lb;
        __builtin_memcpy(&hb, &hf, 2);
        __builtin_memcpy(&lb, &lf, 2);
        aohl[((size_t)(b * 64) + h * 8 + cp) * LL + pix] = (unsigned int)hb | ((unsigned int)lb << 16);
    }
}

// ---------------- Kernel W: pre-split proj_w into MFMA fragment layout ----------------
// wfrag[ks(16)][hl(2)][co(64)][k(64)] halfs; 16B slot index XOR'd with (co&7).
__global__ void wprep_kernel(const float* __restrict__ w, unsigned short* __restrict__ wfrag) {
    const int idx = blockIdx.x * 256 + threadIdx.x;   // 16*64*64 = 65536
    const int k  = idx & 63;
    const int co = (idx >> 6) & 63;
    const int ks = idx >> 12;
    const int kg = ks * 64 + k;
    const int ci = kg >> 4, tap = kg & 15;
    const float vv = (tap < 9) ? w[(co * 64 + ci) * 9 + tap] : 0.f;
    const _Float16 h = (_Float16)vv;
    const _Float16 l = (_Float16)(vv - (float)h);
    unsigned short hb, lb;
    __builtin_memcpy(&hb, &h, 2);
    __builtin_memcpy(&lb, &l, 2);
    const int kx = (((k >> 3) ^ (co & 7)) << 3) | (k & 7);
    wfrag[(((size_t)ks * 2 + 0) * 64 + co) * 64 + kx] = hb;
    wfrag[(((size_t)ks * 2 + 1) * 64 + co) * 64 + kx] = lb;
}

// ---------------- Kernel D: 3x3 conv via MFMA, precomputed hi/lo, XOR-swizzled LDS ----
// grid 512 (XCD-chunk swizzled): block -> (row y, batch b), 128 pix.
// 16 ksteps of K=64 (4 ci), single-buffered. plds[2hl][128pix][64k], wlds[2hl][64co][64k].
__global__ __launch_bounds__(256) void conv_kernel(const unsigned int* __restrict__ aohl,
                                                   const unsigned short* __restrict__ wfrag,
                                                   const float* __restrict__ bias,
                                                   float* __restrict__ out) {
    const int bid = blockIdx.x;
    const int swz = (bid & 7) * 64 + (bid >> 3);   // XCD-chunked: 64 consecutive per XCD
    const int y = swz & 127;
    const int b = swz >> 7;
    const int tid = threadIdx.x;
    const int lane = tid & 63;
    const int wv = tid >> 6;
    const int rl = lane & 15;
    const int g  = lane >> 4;

    __shared__ unsigned short plds[2 * 128 * 64];   // 32768 B
    __shared__ unsigned short wlds[2 * 64 * 64];    // 16384 B

    f32x4 acc[4][2];
#pragma unroll
    for (int ct = 0; ct < 4; ++ct)
#pragma unroll
        for (int pt = 0; pt < 2; ++pt) acc[ct][pt] = (f32x4)0.f;

    const unsigned int* aob = aohl + (size_t)b * 64 * LL;

    for (int ks = 0; ks < 16; ++ks) {
        __syncthreads();   // protect previous kstep's reads
        // ---- stage W: 16 KB linear copy (XOR pre-baked by wprep) ----
        {
            const uint4* wsrc = (const uint4*)(wfrag + (size_t)ks * 8192);
            uint4* wdst = (uint4*)&wlds[0];
#pragma unroll
            for (int i = 0; i < 4; ++i) wdst[i * 256 + tid] = wsrc[i * 256 + tid];
        }
        // ---- stage P: 128 pix x 4 ci; 2 slots per thread ----
#pragma unroll
        for (int sidx = 0; sidx < 2; ++sidx) {
            const int slot = sidx * 256 + tid;      // 0..511
            const int pix = slot & 127;
            const int cisel = slot >> 7;            // 0..3
            const int ci = ks * 4 + cisel;
            const unsigned int* src = aob + (size_t)ci * LL;
            unsigned int p9[9];
#pragma unroll
            for (int dy = 0; dy < 3; ++dy) {
                const int yy = y + dy - 1;
#pragma unroll
                for (int dx = 0; dx < 3; ++dx) {
                    const int xx = pix + dx - 1;
                    const bool ok = (yy >= 0 && yy < HH && xx >= 0 && xx < WW);
                    p9[dy * 3 + dx] = ok ? src[yy * WW + xx] : 0u;
                }
            }
            unsigned short h16[16], l16[16];
#pragma unroll
            for (int j = 0; j < 16; ++j) {
                const unsigned int pv = (j < 9) ? p9[j] : 0u;
                h16[j] = (unsigned short)(pv & 0xffffu);
                l16[j] = (unsigned short)(pv >> 16);
            }
            const int x0 = (((2 * cisel)     ^ (pix & 7)) << 3);
            const int x1 = (((2 * cisel + 1) ^ (pix & 7)) << 3);
            *(u16x8*)&plds[(0 * 128 + pix) * 64 + x0] = *(u16x8*)&h16[0];
            *(u16x8*)&plds[(0 * 128 + pix) * 64 + x1] = *(u16x8*)&h16[8];
            *(u16x8*)&plds[(1 * 128 + pix) * 64 + x0] = *(u16x8*)&l16[0];
            *(u16x8*)&plds[(1 * 128 + pix) * 64 + x1] = *(u16x8*)&l16[8];
        }
        __syncthreads();

        // ---- MFMA: 2 ksubs x 4 co-tiles x 2 pix-tiles x 3 (hi/lo) ----
#pragma unroll
        for (int ksub = 0; ksub < 2; ++ksub) {
            const int xs = (((ksub * 4 + g) ^ (rl & 7)) << 3);
            f16x8 bh[2], bl[2];
#pragma unroll
            for (int pt = 0; pt < 2; ++pt) {
                const int row = wv * 32 + pt * 16 + rl;
                bh[pt] = *(const f16x8*)&plds[(0 * 128 + row) * 64 + xs];
                bl[pt] = *(const f16x8*)&plds[(1 * 128 + row) * 64 + xs];
            }
#pragma unroll
            for (int ct = 0; ct < 4; ++ct) {
                const int rowa = ct * 16 + rl;
                const f16x8 ah = *(const f16x8*)&wlds[(0 * 64 + rowa) * 64 + xs];
                const f16x8 al = *(const f16x8*)&wlds[(1 * 64 + rowa) * 64 + xs];
#pragma unroll
                for (int pt = 0; pt < 2; ++pt) {
                    acc[ct][pt] = __builtin_amdgcn_mfma_f32_16x16x32_f16(ah, bh[pt], acc[ct][pt], 0, 0, 0);
                    acc[ct][pt] = __builtin_amdgcn_mfma_f32_16x16x32_f16(ah, bl[pt], acc[ct][pt], 0, 0, 0);
                    acc[ct][pt] = __builtin_amdgcn_mfma_f32_16x16x32_f16(al, bh[pt], acc[ct][pt], 0, 0, 0);
                }
            }
        }
    }

#pragma unroll
    for (int ct = 0; ct < 4; ++ct) {
        const int co_b = ct * 16 + (lane >> 4) * 4;
#pragma unroll
        for (int pt = 0; pt < 2; ++pt) {
            const int px = wv * 32 + pt * 16 + rl;
#pragma unroll
            for (int j = 0; j < 4; ++j) {
                const int co = co_b + j;
                out[((size_t)b * 64 + co) * LL + y * WW + px] = acc[ct][pt][j] + bias[co];
            }
        }
    }
}

extern "C" void kernel_launch(void* const* d_in, const int* in_sizes, int n_in,
                              void* d_out, int out_size, void* d_ws, size_t ws_size,
                              hipStream_t stream) {
    const float* x      = (const float*)d_in[0];
    const float* qkv_w  = (const float*)d_in[1];
    const float* qkv_b  = (const float*)d_in[2];
    const float* proj_w = (const float*)d_in[3];
    const float* proj_b = (const float*)d_in[4];
    float* out = (float*)d_out;
    float* ws  = (float*)d_ws;

    const size_t n1 = (size_t)4 * 64 * LL;      // one B*C*L plane set
    float* qb   = ws;
    float* kb   = ws + n1;
    float* vb   = ws + 2 * n1;
    unsigned int* aohl = (unsigned int*)(ws + 3 * n1);
    float* KV   = ws + 4 * n1;                  // 4*8*8*9*8 = 18432 floats
    float* KS   = KV + 4 * 8 * 8 * 9 * 8;       // 4*8*8*9  = 2304 floats
    float* KVp  = KS + 4 * 8 * 8 * 9;           // 32*32*648 = 663552 floats
    unsigned short* wfrag = (unsigned short*)(KVp + (size_t)32 * KVCHUNKS * 648);  // 131072 halfs

    wprep_kernel<<<256, 256, 0, stream>>>(proj_w, wfrag);
    qkv_kernel<<<dim3(128, 4, 3), 256, 0, stream>>>(x, qkv_w, qkv_b, qb, kb, vb);
    kv_kernel<<<dim3(KVCHUNKS, NH, 4), 256, 0, stream>>>(kb, vb, KVp);
    kv_finalize<<<32, 256, 0, stream>>>(KVp, KV, KS);
    attn_kernel<<<dim3(128, NH, 4), 128, 0, stream>>>(qb, KV, KS, aohl);
    conv_kernel<<<512, 256, 0, stream>>>(aohl, wfrag, proj_b, out);
}